// Round 8
// baseline (230.473 us; speedup 1.0000x reference)
//
#include <hip/hip_runtime.h>
#include <hip/hip_bf16.h>
#include <math.h>

#define B_      4
#define LQ_     512
#define LKV_    4096
#define IN_DIM_ 1024
#define NH_     16
#define DH_     64
#define INNER_  1024

typedef _Float16 f16x8 __attribute__((ext_vector_type(8)));
typedef _Float16 f16x4 __attribute__((ext_vector_type(4)));
typedef float    f32x4 __attribute__((ext_vector_type(4)));

// async global->LDS, 16B per lane; LDS dest = wave-uniform base + lane*16
#define GLDS(gp, lp) __builtin_amdgcn_global_load_lds( \
    (const __attribute__((address_space(1))) void*)(gp), \
    (__attribute__((address_space(3))) void*)(lp), 16, 0, 0)

// ---------------------------------------------------------------------------
// Per-batch mask scan (coalesced int4 + shfl scan): pidx = excl prefix, cnt.
// ---------------------------------------------------------------------------
__global__ __launch_bounds__(256) void scan_mask(const int* __restrict__ mask,
                                                 int* __restrict__ pidx,
                                                 int* __restrict__ cnt) {
  __shared__ int wsum_s[4];
  int b = blockIdx.x, tid = threadIdx.x;
  const int* mb = mask + b * LKV_;
  int base = tid * 16;
  int vals[16];
#pragma unroll
  for (int i = 0; i < 4; ++i) {
    int4 v = *(const int4*)(mb + base + i * 4);
    vals[i * 4 + 0] = v.x; vals[i * 4 + 1] = v.y;
    vals[i * 4 + 2] = v.z; vals[i * 4 + 3] = v.w;
  }
  int s = 0;
#pragma unroll
  for (int j = 0; j < 16; ++j) s += (vals[j] == 0);
  int lane = tid & 63, wave = tid >> 6;
  int inc = s;
#pragma unroll
  for (int d = 1; d < 64; d <<= 1) {
    int v = __shfl_up(inc, d);
    if (lane >= d) inc += v;
  }
  if (lane == 63) wsum_s[wave] = inc;
  __syncthreads();
  int woff = 0;
#pragma unroll
  for (int w = 0; w < 4; ++w)
    if (w < wave) woff += wsum_s[w];
  if (tid == 255) cnt[b] = woff + inc;
  int run = woff + inc - s;
#pragma unroll
  for (int i = 0; i < 4; ++i) {
    int4 o;
    int* op = &o.x;
#pragma unroll
    for (int j = 0; j < 4; ++j) { op[j] = run; run += (vals[i * 4 + j] == 0); }
    *(int4*)(pidx + b * LKV_ + base + i * 4) = o;
  }
}

// ---------------------------------------------------------------------------
// Fused prep, GRID-STRIDE (R7-verified: -10 us vs 22528 one-shot blocks).
// ids: [0,16384) compact kv | [16384,18432) q cast |
// [18432,19456) Wq^T | [19456,21504) Wkv^T | [21504,22528) Wo^T.
// ---------------------------------------------------------------------------
__device__ __forceinline__ void transpose_tile(const float* __restrict__ in,
                                               _Float16* __restrict__ out,
                                               int K, int N, int xb, int yb,
                                               float (*t)[33]) {
  int bn = xb * 32, bk = yb * 32;
  int tx = threadIdx.x & 31, ty = threadIdx.x >> 5;
#pragma unroll
  for (int i = 0; i < 4; ++i) {
    int r = ty + i * 8;
    t[r][tx] = in[(size_t)(bk + r) * N + bn + tx];
  }
  __syncthreads();
#pragma unroll
  for (int i = 0; i < 4; ++i) {
    int r = ty + i * 8;
    out[(size_t)(bn + r) * K + bk + tx] = (_Float16)t[tx][r];
  }
}

__global__ __launch_bounds__(256) void prep_compact(
    const float* __restrict__ kv, const float* __restrict__ q,
    const float* __restrict__ Wq, const float* __restrict__ Wkv,
    const float* __restrict__ Wo, const int* __restrict__ mask,
    const int* __restrict__ pidx,
    _Float16* __restrict__ kv16, _Float16* __restrict__ q16,
    _Float16* __restrict__ Wqt, _Float16* __restrict__ Wkvt,
    _Float16* __restrict__ Wot) {
  __shared__ float t[32][33];
  const int tid = threadIdx.x;
  for (int id = blockIdx.x; id < 22528; id += (int)gridDim.x) {
    if (id < 16384) {  // compact + cast kv row (mask[id] is block-uniform)
      if (mask[id] == 0) {
        int b = id >> 12;
        int dst = b * LKV_ + pidx[id];
        float4 v = ((const float4*)(kv + (size_t)id * IN_DIM_))[tid];
        f16x4 h = {(_Float16)v.x, (_Float16)v.y, (_Float16)v.z, (_Float16)v.w};
        ((f16x4*)(kv16 + (size_t)dst * IN_DIM_))[tid] = h;
      }
    } else if (id < 18432) {  // q cast
      int i = (id - 16384) * 256 + tid;
      float4 v = ((const float4*)q)[i];
      f16x4 h = {(_Float16)v.x, (_Float16)v.y, (_Float16)v.z, (_Float16)v.w};
      ((f16x4*)q16)[i] = h;
    } else if (id < 19456) {
      int l = id - 18432;
      transpose_tile(Wq, Wqt, 1024, 1024, l & 31, l >> 5, t);
    } else if (id < 21504) {
      int l = id - 19456;
      transpose_tile(Wkv, Wkvt, 1024, 2048, l & 63, l >> 6, t);
    } else {
      int l = id - 21504;
      transpose_tile(Wo, Wot, 1024, 1024, l & 31, l >> 5, t);
    }
    __syncthreads();  // shared t reuse across loop iterations
  }
}

// ---------------------------------------------------------------------------
// Fused projection GEMM, T4 COUNTED-VMCNT 2-PHASE (R8).
// 128x128 tile, BK=64, double-buffered LDS (64 KB -> 2 blocks/CU).
// Per K-step: {stage(t+1) -> s_waitcnt vmcnt(8) -> s_barrier -> compute(t)
// -> s_barrier}. Unlike __syncthreads (vmcnt(0) drain every step, R0-R7) or
// naive dbuf (R3: kept the drain AND halved blocks/CU), the counted wait
// leaves tile t+1's 8 loads in flight across the barrier and under the
// MFMA phase [T4: m218 +38-73%; m230 2ph=682 TF at this tile/BK].
// Safety: stage(t) overwrites buf[(t+1)&1], last read by compute(t-1),
// protected by the trailing barrier; per-wave vmcnt + barrier => all waves'
// tile-t loads landed before any ds_read; final iter waits vmcnt(0).
// blocks [0,2048): kvp -> split Kp / transposed Vt, early exit past cnt[b].
// blocks [2048,2176): qp16 = q16 @ Wqt^T.
// ---------------------------------------------------------------------------
__global__ __launch_bounds__(256, 2) void proj_f16(
    const _Float16* __restrict__ kv16, const _Float16* __restrict__ Wkvt,
    const _Float16* __restrict__ q16, const _Float16* __restrict__ Wqt,
    _Float16* __restrict__ qp16, _Float16* __restrict__ Kp,
    _Float16* __restrict__ Vt, const int* __restrict__ Cnt) {
  const int id = blockIdx.x;
  const bool is_kv = (id < 2048);
  int brow, bcol;
  const _Float16 *Ab, *Bb;
  if (is_kv) {
    bcol = (id & 15) * 128;
    brow = (id >> 4) * 128;
    if ((brow & 4095) >= Cnt[brow >> 12]) return;
    Ab = kv16 + (size_t)brow * 1024;
    Bb = Wkvt + (size_t)bcol * 1024;
  } else {
    int l = id - 2048;
    bcol = (l & 7) * 128;
    brow = (l >> 3) * 128;
    Ab = q16 + (size_t)brow * 1024;
    Bb = Wqt + (size_t)bcol * 1024;
  }
  __shared__ _Float16 As[2][128 * 64];
  __shared__ _Float16 Bs[2][128 * 64];
  const int tid = threadIdx.x;
  const int wave = tid >> 6, lane = tid & 63;
  const int quad = lane >> 4, l16 = lane & 15;
  const int wm = (wave & 1) * 64, wn = (wave >> 1) * 64;
  const int ro8 = lane >> 3, c8 = lane & 7;  // stage: 8 rows x 8 chunks of 16B

  f32x4 acc[4][4];
#pragma unroll
  for (int i = 0; i < 4; ++i)
#pragma unroll
    for (int j = 0; j < 4; ++j) acc[i][j] = (f32x4){0.f, 0.f, 0.f, 0.f};

  auto stage = [&](int p, int k0) {
#pragma unroll
    for (int i = 0; i < 4; ++i) {
      int rbase = wave * 32 + i * 8;
      int row = rbase + ro8;
      int g = c8 ^ (row & 7);  // pre-swizzled source; reader applies same XOR
      GLDS(Ab + (size_t)row * 1024 + k0 + g * 8, &As[p][rbase * 64]);
      GLDS(Bb + (size_t)row * 1024 + k0 + g * 8, &Bs[p][rbase * 64]);
    }
  };
  auto compute = [&](int p) {
#pragma unroll
    for (int ks = 0; ks < 2; ++ks) {
      f16x8 af[4], bf[4];
      int c = ks * 4 + quad;
#pragma unroll
      for (int mt = 0; mt < 4; ++mt) {
        int r = wm + mt * 16 + l16;
        af[mt] = *(const f16x8*)&As[p][r * 64 + ((c ^ (r & 7)) * 8)];
        int rb = wn + mt * 16 + l16;
        bf[mt] = *(const f16x8*)&Bs[p][rb * 64 + ((c ^ (rb & 7)) * 8)];
      }
#pragma unroll
      for (int mt = 0; mt < 4; ++mt)
#pragma unroll
        for (int nt = 0; nt < 4; ++nt)
          acc[mt][nt] = __builtin_amdgcn_mfma_f32_16x16x32_f16(af[mt], bf[nt], acc[mt][nt], 0, 0, 0);
    }
  };

  stage(0, 0);  // 8 loads/thread outstanding (tile 0)
#pragma unroll
  for (int t = 0; t < 16; ++t) {
    const int cur = t & 1;
    if (t < 15) {
      stage(cur ^ 1, (t + 1) * 64);  // +8 (tile t+1), 16 outstanding
      asm volatile("s_waitcnt vmcnt(8)" ::: "memory");  // tile t landed
    } else {
      asm volatile("s_waitcnt vmcnt(0)" ::: "memory");  // last tile landed
    }
    __builtin_amdgcn_s_barrier();  // tile t visible to all waves
    compute(cur);
    if (t < 15) __builtin_amdgcn_s_barrier();  // reads done before overwrite
  }

#pragma unroll
  for (int mt = 0; mt < 4; ++mt) {
    int row0 = brow + wm + mt * 16 + quad * 4;
#pragma unroll
    for (int nt = 0; nt < 4; ++nt) {
      int col = bcol + wn + nt * 16 + l16;
      f32x4 v = acc[mt][nt];
      if (is_kv) {
        int h = col >> 7, w64 = col & 63;
        if ((col & 127) < 64) {  // K half
#pragma unroll
          for (int r = 0; r < 4; ++r)
            Kp[(size_t)(row0 + r) * INNER_ + h * 64 + w64] = (_Float16)v[r];
        } else {  // V half, transposed store: regs = 4 consecutive keys
          int b = row0 >> 12, key = row0 & 4095;
          f16x4 pk = {(_Float16)v[0], (_Float16)v[1], (_Float16)v[2], (_Float16)v[3]};
          *(f16x4*)&Vt[((size_t)((b * NH_ + h) * DH_) + w64) * LKV_ + key] = pk;
        }
      } else {
#pragma unroll
        for (int r = 0; r < 4; ++r)
          qp16[(size_t)(row0 + r) * 1024 + col] = (_Float16)v[r];
      }
    }
  }
}

// ---------------------------------------------------------------------------
// Flash attention, NO key-split (R5). Grid 512: bh=id&63, qt=id>>6.
// Each block walks all key tiles, normalizes in-register, writes ctx16 f16.
// Fixed-shift softmax p=exp(s-8) (scores bounded) -> pure sums.
// launch_bounds(256,2): (256,3) cost +16 us measured twice (VGPR spill).
// ---------------------------------------------------------------------------
__global__ __launch_bounds__(256, 2) void attn_f16(
    const _Float16* __restrict__ qp, const _Float16* __restrict__ Kp,
    const _Float16* __restrict__ Vt, const int* __restrict__ cnt,
    _Float16* __restrict__ ctx) {
  const int idx = blockIdx.x;
  const int bh = idx & 63, qt = idx >> 6;
  const int b = bh >> 4, h = bh & 15;
  __shared__ _Float16 Ks[128 * 64];    // [key][dim], 8-chunk XOR swizzle
  __shared__ _Float16 Vts[64 * 128];   // [dim][key], 16-chunk XOR swizzle
  __shared__ _Float16 Pl[64][136];     // [query][key], +8 pad

  const int tid = threadIdx.x;
  const int wave = tid >> 6, lane = tid & 63;
  const int quad = lane >> 4, l16 = lane & 15;
  const int ro8 = lane >> 3, gch8 = (lane & 7) ^ (ro8 & 7);
  const int ro16 = lane >> 4, ch16 = lane & 15;

  const int qrow = b * LQ_ + qt * 64 + wave * 16 + l16;
  const _Float16* qpr = qp + (size_t)qrow * INNER_ + h * DH_;
  f16x8 qf[2];
  qf[0] = *(const f16x8*)(qpr + quad * 8);
  qf[1] = *(const f16x8*)(qpr + 32 + quad * 8);

  const int c_act = cnt[b];
  const int tiles = (c_act + 127) >> 7;

  float l_run = 0.f;
  f32x4 oacc[4];
#pragma unroll
  for (int i = 0; i < 4; ++i) oacc[i] = (f32x4){0.f, 0.f, 0.f, 0.f};

  const _Float16* kb = Kp + (size_t)(b * LKV_) * INNER_ + h * DH_;
  const _Float16* vb = Vt + (size_t)((b * NH_ + h) * DH_) * LKV_;

  for (int t = 0; t < tiles; ++t) {
    __syncthreads();  // prev-iter LDS reads done
#pragma unroll
    for (int i = 0; i < 4; ++i) {
      int rbase = wave * 32 + i * 8;
      GLDS(kb + (size_t)(t * 128 + rbase + ro8) * INNER_ + gch8 * 8, &Ks[rbase * 64]);
    }
#pragma unroll
    for (int i = 0; i < 4; ++i) {
      int rbase = wave * 16 + i * 4;
      int row = rbase + ro16;
      int gch = ch16 ^ (row & 15);
      GLDS(vb + (size_t)row * LKV_ + t * 128 + gch * 8, &Vts[rbase * 128]);
    }
    __syncthreads();  // staged data visible

    // S^T = K . Q^T
    f32x4 sacc[8];
#pragma unroll
    for (int i = 0; i < 8; ++i) sacc[i] = (f32x4){0.f, 0.f, 0.f, 0.f};
#pragma unroll
    for (int ks = 0; ks < 2; ++ks) {
      int c = ks * 4 + quad;
#pragma unroll
      for (int mt = 0; mt < 8; ++mt) {
        int krow = mt * 16 + l16;
        f16x8 af = *(const f16x8*)&Ks[krow * 64 + ((c ^ (krow & 7)) * 8)];
        sacc[mt] = __builtin_amdgcn_mfma_f32_16x16x32_f16(af, qf[ks], sacc[mt], 0, 0, 0);
      }
    }
    // scale + tail mask + exp(s-8) + P pack
    const int lim = c_act - t * 128;
    float psloc = 0.f;
#pragma unroll
    for (int mt = 0; mt < 8; ++mt) {
      f16x4 pk;
#pragma unroll
      for (int r = 0; r < 4; ++r) {
        int key = mt * 16 + quad * 4 + r;
        float s = sacc[mt][r] * 0.125f;
        if (key >= lim) s = -1e30f;
        float p = __expf(s - 8.0f);
        psloc += p;
        pk[r] = (_Float16)p;
      }
      *(f16x4*)&Pl[wave * 16 + l16][mt * 16 + quad * 4] = pk;
    }
    psloc += __shfl_xor(psloc, 16);
    psloc += __shfl_xor(psloc, 32);
    l_run += psloc;
    // O^T += V^T . P^T (within-wave Pl dep: lgkmcnt-ordered, no barrier)
#pragma unroll
    for (int ks = 0; ks < 4; ++ks) {
      int c = ks * 4 + quad;
      f16x8 bf = *(const f16x8*)&Pl[wave * 16 + l16][ks * 32 + quad * 8];
#pragma unroll
      for (int mt = 0; mt < 4; ++mt) {
        int drow = mt * 16 + l16;
        f16x8 af = *(const f16x8*)&Vts[drow * 128 + ((c ^ (drow & 15)) * 8)];
        oacc[mt] = __builtin_amdgcn_mfma_f32_16x16x32_f16(af, bf, oacc[mt], 0, 0, 0);
      }
    }
  }

  // normalize in-register and write ctx16 f16 directly (no partials/fin)
  const float inv = (l_run > 0.f) ? 1.f / l_run : 0.f;
  _Float16* cb = ctx + (size_t)qrow * INNER_ + h * DH_;
#pragma unroll
  for (int mt = 0; mt < 4; ++mt) {
    f16x4 o;
#pragma unroll
    for (int r = 0; r < 4; ++r) o[r] = (_Float16)(oacc[mt][r] * inv);
    *(f16x4*)(cb + mt * 16 + quad * 4) = o;
  }
}

// ---------------------------------------------------------------------------
// Output GEMM: out[2048][1024] f32 = ctx16 @ Wot^T. 64x64 tiles -> 512
// blocks = 2 blocks/CU. BK=64, 16 KB LDS, 2-barrier structure.
// ---------------------------------------------------------------------------
__global__ __launch_bounds__(256, 2) void gemm_out(
    const _Float16* __restrict__ A, const _Float16* __restrict__ Bt,
    float* __restrict__ C) {
  const int brow = blockIdx.y * 64, bcol = blockIdx.x * 64;
  __shared__ _Float16 As[64 * 64];
  __shared__ _Float16 Bs[64 * 64];
  const int tid = threadIdx.x;
  const int wave = tid >> 6, lane = tid & 63;
  const int quad = lane >> 4, l16 = lane & 15;
  const int wm = (wave & 1) * 32, wn = (wave >> 1) * 32;
  const int ro8 = lane >> 3, c8 = lane & 7;

  f32x4 acc[2][2];
#pragma unroll
  for (int i = 0; i < 2; ++i)
#pragma unroll
    for (int j = 0; j < 2; ++j) acc[i][j] = (f32x4){0.f, 0.f, 0.f, 0.f};

  const _Float16* Ab = A + (size_t)brow * 1024;
  const _Float16* Bb = Bt + (size_t)bcol * 1024;

  for (int k0 = 0; k0 < 1024; k0 += 64) {
    __syncthreads();
#pragma unroll
    for (int i = 0; i < 2; ++i) {
      int rbase = wave * 16 + i * 8;
      int row = rbase + ro8;
      int g = c8 ^ (row & 7);
      GLDS(Ab + (size_t)row * 1024 + k0 + g * 8, &As[rbase * 64]);
      GLDS(Bb + (size_t)row * 1024 + k0 + g * 8, &Bs[rbase * 64]);
    }
    __syncthreads();
#pragma unroll
    for (int ks = 0; ks < 2; ++ks) {
      f16x8 af[2], bf[2];
      int c = ks * 4 + quad;
#pragma unroll
      for (int mt = 0; mt < 2; ++mt) {
        int r = wm + mt * 16 + l16;
        af[mt] = *(const f16x8*)&As[r * 64 + ((c ^ (r & 7)) * 8)];
        int rb = wn + mt * 16 + l16;
        bf[mt] = *(const f16x8*)&Bs[rb * 64 + ((c ^ (rb & 7)) * 8)];
      }
#pragma unroll
      for (int mt = 0; mt < 2; ++mt)
#pragma unroll
        for (int nt = 0; nt < 2; ++nt)
          acc[mt][nt] = __builtin_amdgcn_mfma_f32_16x16x32_f16(af[mt], bf[nt], acc[mt][nt], 0, 0, 0);
    }
  }

#pragma unroll
  for (int mt = 0; mt < 2; ++mt) {
    int row0 = brow + wm + mt * 16 + quad * 4;
#pragma unroll
    for (int nt = 0; nt < 2; ++nt) {
      int col = bcol + wn + nt * 16 + l16;
      f32x4 v = acc[mt][nt];
#pragma unroll
      for (int r = 0; r < 4; ++r) C[(size_t)(row0 + r) * 1024 + col] = v[r];
    }
  }
}

// ---------------------------------------------------------------------------
extern "C" void kernel_launch(void* const* d_in, const int* in_sizes, int n_in,
                              void* d_out, int out_size, void* d_ws, size_t ws_size,
                              hipStream_t stream) {
  const float* q   = (const float*)d_in[0];
  const float* kv  = (const float*)d_in[1];
  const int* mask  = (const int*)d_in[2];
  const float* Wq  = (const float*)d_in[3];
  const float* Wkv = (const float*)d_in[4];
  const float* Wo  = (const float*)d_in[5];
  float* out = (float*)d_out;

  _Float16* p = (_Float16*)d_ws;
  _Float16* q16   = p; p += (size_t)2048 * 1024;
  _Float16* kv16  = p; p += (size_t)16384 * 1024;  // compacted per-batch
  _Float16* Wqt   = p; p += (size_t)1024 * 1024;
  _Float16* Wkvt  = p; p += (size_t)2048 * 1024;
  _Float16* Wot   = p; p += (size_t)1024 * 1024;
  _Float16* qp16  = p; p += (size_t)2048 * 1024;
  _Float16* Kp    = p; p += (size_t)16384 * 1024;
  _Float16* Vt    = p; p += (size_t)16384 * 1024;
  _Float16* ctx16 = p; p += (size_t)2048 * 1024;
  int* pidx = (int*)p;
  int* cnt  = pidx + 16384;

  scan_mask<<<4, 256, 0, stream>>>(mask, pidx, cnt);
  prep_compact<<<2816, 256, 0, stream>>>(kv, q, Wq, Wkv, Wo, mask, pidx,
                                         kv16, q16, Wqt, Wkvt, Wot);
  proj_f16<<<2176, 256, 0, stream>>>(kv16, Wkvt, q16, Wqt, qp16, Kp, Vt, cnt);
  attn_f16<<<512, 256, 0, stream>>>(qp16, Kp, Vt, cnt, ctx16);
  gemm_out<<<dim3(16, 32), 256, 0, stream>>>(ctx16, Wot, out);
}

// Round 9
// 222.503 us; speedup vs baseline: 1.0358x; 1.0358x over previous
//
#include <hip/hip_runtime.h>
#include <hip/hip_bf16.h>
#include <math.h>

#define B_      4
#define LQ_     512
#define LKV_    4096
#define IN_DIM_ 1024
#define NH_     16
#define DH_     64
#define INNER_  1024

typedef _Float16 f16x8 __attribute__((ext_vector_type(8)));
typedef _Float16 f16x4 __attribute__((ext_vector_type(4)));
typedef float    f32x4 __attribute__((ext_vector_type(4)));

// async global->LDS, 16B per lane; LDS dest = wave-uniform base + lane*16
#define GLDS(gp, lp) __builtin_amdgcn_global_load_lds( \
    (const __attribute__((address_space(1))) void*)(gp), \
    (__attribute__((address_space(3))) void*)(lp), 16, 0, 0)

// ---------------------------------------------------------------------------
// Per-batch mask scan (coalesced int4 + shfl scan): pidx = excl prefix, cnt.
// ---------------------------------------------------------------------------
__global__ __launch_bounds__(256) void scan_mask(const int* __restrict__ mask,
                                                 int* __restrict__ pidx,
                                                 int* __restrict__ cnt) {
  __shared__ int wsum_s[4];
  int b = blockIdx.x, tid = threadIdx.x;
  const int* mb = mask + b * LKV_;
  int base = tid * 16;
  int vals[16];
#pragma unroll
  for (int i = 0; i < 4; ++i) {
    int4 v = *(const int4*)(mb + base + i * 4);
    vals[i * 4 + 0] = v.x; vals[i * 4 + 1] = v.y;
    vals[i * 4 + 2] = v.z; vals[i * 4 + 3] = v.w;
  }
  int s = 0;
#pragma unroll
  for (int j = 0; j < 16; ++j) s += (vals[j] == 0);
  int lane = tid & 63, wave = tid >> 6;
  int inc = s;
#pragma unroll
  for (int d = 1; d < 64; d <<= 1) {
    int v = __shfl_up(inc, d);
    if (lane >= d) inc += v;
  }
  if (lane == 63) wsum_s[wave] = inc;
  __syncthreads();
  int woff = 0;
#pragma unroll
  for (int w = 0; w < 4; ++w)
    if (w < wave) woff += wsum_s[w];
  if (tid == 255) cnt[b] = woff + inc;
  int run = woff + inc - s;
#pragma unroll
  for (int i = 0; i < 4; ++i) {
    int4 o;
    int* op = &o.x;
#pragma unroll
    for (int j = 0; j < 4; ++j) { op[j] = run; run += (vals[i * 4 + j] == 0); }
    *(int4*)(pidx + b * LKV_ + base + i * 4) = o;
  }
}

// ---------------------------------------------------------------------------
// Fused prep, GRID-STRIDE (R7-verified: -10 us vs 22528 one-shot blocks).
// ids: [0,16384) compact kv | [16384,18432) q cast |
// [18432,19456) Wq^T | [19456,21504) Wkv^T | [21504,22528) Wo^T.
// ---------------------------------------------------------------------------
__device__ __forceinline__ void transpose_tile(const float* __restrict__ in,
                                               _Float16* __restrict__ out,
                                               int K, int N, int xb, int yb,
                                               float (*t)[33]) {
  int bn = xb * 32, bk = yb * 32;
  int tx = threadIdx.x & 31, ty = threadIdx.x >> 5;
#pragma unroll
  for (int i = 0; i < 4; ++i) {
    int r = ty + i * 8;
    t[r][tx] = in[(size_t)(bk + r) * N + bn + tx];
  }
  __syncthreads();
#pragma unroll
  for (int i = 0; i < 4; ++i) {
    int r = ty + i * 8;
    out[(size_t)(bn + r) * K + bk + tx] = (_Float16)t[tx][r];
  }
}

__global__ __launch_bounds__(256) void prep_compact(
    const float* __restrict__ kv, const float* __restrict__ q,
    const float* __restrict__ Wq, const float* __restrict__ Wkv,
    const float* __restrict__ Wo, const int* __restrict__ mask,
    const int* __restrict__ pidx,
    _Float16* __restrict__ kv16, _Float16* __restrict__ q16,
    _Float16* __restrict__ Wqt, _Float16* __restrict__ Wkvt,
    _Float16* __restrict__ Wot) {
  __shared__ float t[32][33];
  const int tid = threadIdx.x;
  for (int id = blockIdx.x; id < 22528; id += (int)gridDim.x) {
    if (id < 16384) {  // compact + cast kv row (mask[id] is block-uniform)
      if (mask[id] == 0) {
        int b = id >> 12;
        int dst = b * LKV_ + pidx[id];
        float4 v = ((const float4*)(kv + (size_t)id * IN_DIM_))[tid];
        f16x4 h = {(_Float16)v.x, (_Float16)v.y, (_Float16)v.z, (_Float16)v.w};
        ((f16x4*)(kv16 + (size_t)dst * IN_DIM_))[tid] = h;
      }
    } else if (id < 18432) {  // q cast
      int i = (id - 16384) * 256 + tid;
      float4 v = ((const float4*)q)[i];
      f16x4 h = {(_Float16)v.x, (_Float16)v.y, (_Float16)v.z, (_Float16)v.w};
      ((f16x4*)q16)[i] = h;
    } else if (id < 19456) {
      int l = id - 18432;
      transpose_tile(Wq, Wqt, 1024, 1024, l & 31, l >> 5, t);
    } else if (id < 21504) {
      int l = id - 19456;
      transpose_tile(Wkv, Wkvt, 1024, 2048, l & 63, l >> 6, t);
    } else {
      int l = id - 21504;
      transpose_tile(Wo, Wot, 1024, 1024, l & 31, l >> 5, t);
    }
    __syncthreads();  // shared t reuse across loop iterations
  }
}

// ---------------------------------------------------------------------------
// Fused projection GEMM (fp16 MFMA, 128x128 tile, BK=64 -> 16 K-steps,
// 2-barrier structure, 32 KB LDS -> 4 blocks/CU). R5-form REVERTED here
// after R8's T4 counted-vmcnt test came back neutral (61.4 us, MfmaUtil 26,
// occ 15.8): the in-flight-across-barrier gain exactly paid for the lost
// blocks/CU. At 56.5 us this structure runs ~685 TF = m230's documented
// 2-phase ceiling (682 TF) -- proj is AT its structure's ceiling; only a
// 256^2 8-phase restructure goes beyond.
// blocks [0,2048): kvp -> split Kp / transposed Vt, early exit past cnt[b].
// blocks [2048,2176): qp16 = q16 @ Wqt^T.
// ---------------------------------------------------------------------------
__global__ __launch_bounds__(256, 4) void proj_f16(
    const _Float16* __restrict__ kv16, const _Float16* __restrict__ Wkvt,
    const _Float16* __restrict__ q16, const _Float16* __restrict__ Wqt,
    _Float16* __restrict__ qp16, _Float16* __restrict__ Kp,
    _Float16* __restrict__ Vt, const int* __restrict__ Cnt) {
  const int id = blockIdx.x;
  const bool is_kv = (id < 2048);
  int brow, bcol;
  const _Float16 *Ab, *Bb;
  if (is_kv) {
    bcol = (id & 15) * 128;
    brow = (id >> 4) * 128;
    if ((brow & 4095) >= Cnt[brow >> 12]) return;
    Ab = kv16 + (size_t)brow * 1024;
    Bb = Wkvt + (size_t)bcol * 1024;
  } else {
    int l = id - 2048;
    bcol = (l & 7) * 128;
    brow = (l >> 3) * 128;
    Ab = q16 + (size_t)brow * 1024;
    Bb = Wqt + (size_t)bcol * 1024;
  }
  __shared__ _Float16 As[128 * 64];
  __shared__ _Float16 Bs[128 * 64];
  const int tid = threadIdx.x;
  const int wave = tid >> 6, lane = tid & 63;
  const int quad = lane >> 4, l16 = lane & 15;
  const int wm = (wave & 1) * 64, wn = (wave >> 1) * 64;
  const int ro8 = lane >> 3, c8 = lane & 7;  // stage: 8 rows x 8 chunks of 16B

  f32x4 acc[4][4];
#pragma unroll
  for (int i = 0; i < 4; ++i)
#pragma unroll
    for (int j = 0; j < 4; ++j) acc[i][j] = (f32x4){0.f, 0.f, 0.f, 0.f};

  for (int k0 = 0; k0 < 1024; k0 += 64) {
    __syncthreads();
#pragma unroll
    for (int i = 0; i < 4; ++i) {
      int rbase = wave * 32 + i * 8;
      int row = rbase + ro8;
      int g = c8 ^ (row & 7);  // pre-swizzled source; reader applies same XOR
      GLDS(Ab + (size_t)row * 1024 + k0 + g * 8, &As[rbase * 64]);
      GLDS(Bb + (size_t)row * 1024 + k0 + g * 8, &Bs[rbase * 64]);
    }
    __syncthreads();
#pragma unroll
    for (int ks = 0; ks < 2; ++ks) {
      f16x8 af[4], bf[4];
      int c = ks * 4 + quad;
#pragma unroll
      for (int mt = 0; mt < 4; ++mt) {
        int r = wm + mt * 16 + l16;
        af[mt] = *(const f16x8*)&As[r * 64 + ((c ^ (r & 7)) * 8)];
        int rb = wn + mt * 16 + l16;
        bf[mt] = *(const f16x8*)&Bs[rb * 64 + ((c ^ (rb & 7)) * 8)];
      }
#pragma unroll
      for (int mt = 0; mt < 4; ++mt)
#pragma unroll
        for (int nt = 0; nt < 4; ++nt)
          acc[mt][nt] = __builtin_amdgcn_mfma_f32_16x16x32_f16(af[mt], bf[nt], acc[mt][nt], 0, 0, 0);
    }
  }

#pragma unroll
  for (int mt = 0; mt < 4; ++mt) {
    int row0 = brow + wm + mt * 16 + quad * 4;
#pragma unroll
    for (int nt = 0; nt < 4; ++nt) {
      int col = bcol + wn + nt * 16 + l16;
      f32x4 v = acc[mt][nt];
      if (is_kv) {
        int h = col >> 7, w64 = col & 63;
        if ((col & 127) < 64) {  // K half
#pragma unroll
          for (int r = 0; r < 4; ++r)
            Kp[(size_t)(row0 + r) * INNER_ + h * 64 + w64] = (_Float16)v[r];
        } else {  // V half, transposed store: regs = 4 consecutive keys
          int b = row0 >> 12, key = row0 & 4095;
          f16x4 pk = {(_Float16)v[0], (_Float16)v[1], (_Float16)v[2], (_Float16)v[3]};
          *(f16x4*)&Vt[((size_t)((b * NH_ + h) * DH_) + w64) * LKV_ + key] = pk;
        }
      } else {
#pragma unroll
        for (int r = 0; r < 4; ++r)
          qp16[(size_t)(row0 + r) * 1024 + col] = (_Float16)v[r];
      }
    }
  }
}

// ---------------------------------------------------------------------------
// Flash attention, NO key-split (R5), V-LATE STAGING (R9): issue K loads
// then V loads; vmcnt(4)+barrier releases QK^T with V's 4 loads still in
// flight (~500cy HBM latency hidden under QK^T+softmax); vmcnt(0)+barrier
// before PV. Zero occupancy cost (unlike proj-T4): pure overlap.
// Grid 512: bh=id&63, qt=id>>6. Fixed-shift softmax p=exp(s-8).
// launch_bounds(256,2): (256,3) cost +16 us measured twice (VGPR spill).
// ---------------------------------------------------------------------------
__global__ __launch_bounds__(256, 2) void attn_f16(
    const _Float16* __restrict__ qp, const _Float16* __restrict__ Kp,
    const _Float16* __restrict__ Vt, const int* __restrict__ cnt,
    _Float16* __restrict__ ctx) {
  const int idx = blockIdx.x;
  const int bh = idx & 63, qt = idx >> 6;
  const int b = bh >> 4, h = bh & 15;
  __shared__ _Float16 Ks[128 * 64];    // [key][dim], 8-chunk XOR swizzle
  __shared__ _Float16 Vts[64 * 128];   // [dim][key], 16-chunk XOR swizzle
  __shared__ _Float16 Pl[64][136];     // [query][key], +8 pad

  const int tid = threadIdx.x;
  const int wave = tid >> 6, lane = tid & 63;
  const int quad = lane >> 4, l16 = lane & 15;
  const int ro8 = lane >> 3, gch8 = (lane & 7) ^ (ro8 & 7);
  const int ro16 = lane >> 4, ch16 = lane & 15;

  const int qrow = b * LQ_ + qt * 64 + wave * 16 + l16;
  const _Float16* qpr = qp + (size_t)qrow * INNER_ + h * DH_;
  f16x8 qf[2];
  qf[0] = *(const f16x8*)(qpr + quad * 8);
  qf[1] = *(const f16x8*)(qpr + 32 + quad * 8);

  const int c_act = cnt[b];
  const int tiles = (c_act + 127) >> 7;

  float l_run = 0.f;
  f32x4 oacc[4];
#pragma unroll
  for (int i = 0; i < 4; ++i) oacc[i] = (f32x4){0.f, 0.f, 0.f, 0.f};

  const _Float16* kb = Kp + (size_t)(b * LKV_) * INNER_ + h * DH_;
  const _Float16* vb = Vt + (size_t)((b * NH_ + h) * DH_) * LKV_;

  for (int t = 0; t < tiles; ++t) {
    __syncthreads();  // prev-iter LDS reads done (lgkm+vm drained)
    // K loads first (4/thread), then V (4/thread): program order => vmcnt(4)
    // waits exactly for K.
#pragma unroll
    for (int i = 0; i < 4; ++i) {
      int rbase = wave * 32 + i * 8;
      GLDS(kb + (size_t)(t * 128 + rbase + ro8) * INNER_ + gch8 * 8, &Ks[rbase * 64]);
    }
#pragma unroll
    for (int i = 0; i < 4; ++i) {
      int rbase = wave * 16 + i * 4;
      int row = rbase + ro16;
      int gch = ch16 ^ (row & 15);
      GLDS(vb + (size_t)row * LKV_ + t * 128 + gch * 8, &Vts[rbase * 128]);
    }
    asm volatile("s_waitcnt vmcnt(4)" ::: "memory");  // own K landed
    __builtin_amdgcn_s_barrier();                     // all waves' K visible

    // S^T = K . Q^T  (V's 4 loads still in flight underneath)
    f32x4 sacc[8];
#pragma unroll
    for (int i = 0; i < 8; ++i) sacc[i] = (f32x4){0.f, 0.f, 0.f, 0.f};
#pragma unroll
    for (int ks = 0; ks < 2; ++ks) {
      int c = ks * 4 + quad;
#pragma unroll
      for (int mt = 0; mt < 8; ++mt) {
        int krow = mt * 16 + l16;
        f16x8 af = *(const f16x8*)&Ks[krow * 64 + ((c ^ (krow & 7)) * 8)];
        sacc[mt] = __builtin_amdgcn_mfma_f32_16x16x32_f16(af, qf[ks], sacc[mt], 0, 0, 0);
      }
    }
    asm volatile("s_waitcnt vmcnt(0)" ::: "memory");  // own V landed
    // scale + tail mask + exp(s-8) + P pack
    const int lim = c_act - t * 128;
    float psloc = 0.f;
#pragma unroll
    for (int mt = 0; mt < 8; ++mt) {
      f16x4 pk;
#pragma unroll
      for (int r = 0; r < 4; ++r) {
        int key = mt * 16 + quad * 4 + r;
        float s = sacc[mt][r] * 0.125f;
        if (key >= lim) s = -1e30f;
        float p = __expf(s - 8.0f);
        psloc += p;
        pk[r] = (_Float16)p;
      }
      *(f16x4*)&Pl[wave * 16 + l16][mt * 16 + quad * 4] = pk;
    }
    psloc += __shfl_xor(psloc, 16);
    psloc += __shfl_xor(psloc, 32);
    l_run += psloc;
    __builtin_amdgcn_s_barrier();  // all waves' V visible (Pl is same-wave)
    // O^T += V^T . P^T
#pragma unroll
    for (int ks = 0; ks < 4; ++ks) {
      int c = ks * 4 + quad;
      f16x8 bf = *(const f16x8*)&Pl[wave * 16 + l16][ks * 32 + quad * 8];
#pragma unroll
      for (int mt = 0; mt < 4; ++mt) {
        int drow = mt * 16 + l16;
        f16x8 af = *(const f16x8*)&Vts[drow * 128 + ((c ^ (drow & 15)) * 8)];
        oacc[mt] = __builtin_amdgcn_mfma_f32_16x16x32_f16(af, bf, oacc[mt], 0, 0, 0);
      }
    }
  }

  // normalize in-register and write ctx16 f16 directly (no partials/fin)
  const float inv = (l_run > 0.f) ? 1.f / l_run : 0.f;
  _Float16* cb = ctx + (size_t)qrow * INNER_ + h * DH_;
#pragma unroll
  for (int mt = 0; mt < 4; ++mt) {
    f16x4 o;
#pragma unroll
    for (int r = 0; r < 4; ++r) o[r] = (_Float16)(oacc[mt][r] * inv);
    *(f16x4*)(cb + mt * 16 + quad * 4) = o;
  }
}

// ---------------------------------------------------------------------------
// Output GEMM: out[2048][1024] f32 = ctx16 @ Wot^T. 64x64 tiles -> 512
// blocks = 2 blocks/CU. BK=64, 16 KB LDS, 2-barrier structure.
// ---------------------------------------------------------------------------
__global__ __launch_bounds__(256, 2) void gemm_out(
    const _Float16* __restrict__ A, const _Float16* __restrict__ Bt,
    float* __restrict__ C) {
  const int brow = blockIdx.y * 64, bcol = blockIdx.x * 64;
  __shared__ _Float16 As[64 * 64];
  __shared__ _Float16 Bs[64 * 64];
  const int tid = threadIdx.x;
  const int wave = tid >> 6, lane = tid & 63;
  const int quad = lane >> 4, l16 = lane & 15;
  const int wm = (wave & 1) * 32, wn = (wave >> 1) * 32;
  const int ro8 = lane >> 3, c8 = lane & 7;

  f32x4 acc[2][2];
#pragma unroll
  for (int i = 0; i < 2; ++i)
#pragma unroll
    for (int j = 0; j < 2; ++j) acc[i][j] = (f32x4){0.f, 0.f, 0.f, 0.f};

  const _Float16* Ab = A + (size_t)brow * 1024;
  const _Float16* Bb = Bt + (size_t)bcol * 1024;

  for (int k0 = 0; k0 < 1024; k0 += 64) {
    __syncthreads();
#pragma unroll
    for (int i = 0; i < 2; ++i) {
      int rbase = wave * 16 + i * 8;
      int row = rbase + ro8;
      int g = c8 ^ (row & 7);
      GLDS(Ab + (size_t)row * 1024 + k0 + g * 8, &As[rbase * 64]);
      GLDS(Bb + (size_t)row * 1024 + k0 + g * 8, &Bs[rbase * 64]);
    }
    __syncthreads();
#pragma unroll
    for (int ks = 0; ks < 2; ++ks) {
      f16x8 af[2], bf[2];
      int c = ks * 4 + quad;
#pragma unroll
      for (int mt = 0; mt < 2; ++mt) {
        int r = wm + mt * 16 + l16;
        af[mt] = *(const f16x8*)&As[r * 64 + ((c ^ (r & 7)) * 8)];
        int rb = wn + mt * 16 + l16;
        bf[mt] = *(const f16x8*)&Bs[rb * 64 + ((c ^ (rb & 7)) * 8)];
      }
#pragma unroll
      for (int mt = 0; mt < 2; ++mt)
#pragma unroll
        for (int nt = 0; nt < 2; ++nt)
          acc[mt][nt] = __builtin_amdgcn_mfma_f32_16x16x32_f16(af[mt], bf[nt], acc[mt][nt], 0, 0, 0);
    }
  }

#pragma unroll
  for (int mt = 0; mt < 2; ++mt) {
    int row0 = brow + wm + mt * 16 + quad * 4;
#pragma unroll
    for (int nt = 0; nt < 2; ++nt) {
      int col = bcol + wn + nt * 16 + l16;
      f32x4 v = acc[mt][nt];
#pragma unroll
      for (int r = 0; r < 4; ++r) C[(size_t)(row0 + r) * 1024 + col] = v[r];
    }
  }
}

// ---------------------------------------------------------------------------
extern "C" void kernel_launch(void* const* d_in, const int* in_sizes, int n_in,
                              void* d_out, int out_size, void* d_ws, size_t ws_size,
                              hipStream_t stream) {
  const float* q   = (const float*)d_in[0];
  const float* kv  = (const float*)d_in[1];
  const int* mask  = (const int*)d_in[2];
  const float* Wq  = (const float*)d_in[3];
  const float* Wkv = (const float*)d_in[4];
  const float* Wo  = (const float*)d_in[5];
  float* out = (float*)d_out;

  _Float16* p = (_Float16*)d_ws;
  _Float16* q16   = p; p += (size_t)2048 * 1024;
  _Float16* kv16  = p; p += (size_t)16384 * 1024;  // compacted per-batch
  _Float16* Wqt   = p; p += (size_t)1024 * 1024;
  _Float16* Wkvt  = p; p += (size_t)2048 * 1024;
  _Float16* Wot   = p; p += (size_t)1024 * 1024;
  _Float16* qp16  = p; p += (size_t)2048 * 1024;
  _Float16* Kp    = p; p += (size_t)16384 * 1024;
  _Float16* Vt    = p; p += (size_t)16384 * 1024;
  _Float16* ctx16 = p; p += (size_t)2048 * 1024;
  int* pidx = (int*)p;
  int* cnt  = pidx + 16384;

  scan_mask<<<4, 256, 0, stream>>>(mask, pidx, cnt);
  prep_compact<<<2816, 256, 0, stream>>>(kv, q, Wq, Wkv, Wo, mask, pidx,
                                         kv16, q16, Wqt, Wkvt, Wot);
  proj_f16<<<2176, 256, 0, stream>>>(kv16, Wkvt, q16, Wqt, qp16, Kp, Vt, cnt);
  attn_f16<<<512, 256, 0, stream>>>(qp16, Kp, Vt, cnt, ctx16);
  gemm_out<<<dim3(16, 32), 256, 0, stream>>>(ctx16, Wot, out);
}